// Round 3
// baseline (223.754 us; speedup 1.0000x reference)
//
#include <hip/hip_runtime.h>
#include <cstdint>

__device__ __forceinline__ float leaky(float v) { return v >= 0.f ? v : 0.01f * v; }

// ================= Encoder: conv5x5 pad2 + leaky + fused 2x2 maxpool =================
template<int R, int CI, int CO, int COG>
__global__ void __launch_bounds__(256) enc_k(
    const float* __restrict__ src1, const float* __restrict__ src2,
    const float* __restrict__ w, const float* __restrict__ bias,
    float* __restrict__ c2, float* __restrict__ pout)
{
    constexpr int W = R, H = R, Wt = R / 2;
    constexpr int RPB = 256 / Wt;              // rows per block (even)
    __shared__ float ws[COG * CI * 25];
    __shared__ float pl[(RPB / 2) * COG * Wt];

    int t = threadIdx.x;
    int gid = blockIdx.x * 256 + t;
    int col = gid % Wt;
    int y = (gid / Wt) % H;
    int n = (gid / (Wt * H)) & 3;
    int g = gid / (Wt * H * 4);

    for (int i = t; i < COG * CI * 25; i += 256) ws[i] = w[g * COG * CI * 25 + i];
    __syncthreads();

    const float* sp = (n < 2) ? (src1 + (size_t)n * CI * H * W)
                              : (src2 + (size_t)(n - 2) * CI * H * W);
    int x0 = col * 2;

    float acc[COG][2];
#pragma unroll
    for (int cg = 0; cg < COG; ++cg) { float b0 = bias[g * COG + cg]; acc[cg][0] = b0; acc[cg][1] = b0; }

    bool okr[5], okc[3];
#pragma unroll
    for (int i = 0; i < 5; ++i) { int yy = y + i - 2; okr[i] = (yy >= 0) && (yy < H); }
#pragma unroll
    for (int j = 0; j < 3; ++j) { int xx = x0 + 2 * j - 2; okc[j] = (xx >= 0) && (xx < W); }

    for (int ci = 0; ci < CI; ++ci) {
        const float* s = sp + ci * H * W + (y - 2) * W + (x0 - 2);
        float p[5][6];
#pragma unroll
        for (int i = 0; i < 5; ++i) {
#pragma unroll
            for (int j = 0; j < 3; ++j) {
                if (okr[i] & okc[j]) {
                    float2 v = *(const float2*)(s + i * W + 2 * j);
                    p[i][2 * j] = v.x; p[i][2 * j + 1] = v.y;
                } else { p[i][2 * j] = 0.f; p[i][2 * j + 1] = 0.f; }
            }
        }
#pragma unroll
        for (int cg = 0; cg < COG; ++cg) {
#pragma unroll
            for (int dy = 0; dy < 5; ++dy) {
#pragma unroll
                for (int dx = 0; dx < 5; ++dx) {
                    float wv = ws[(cg * CI + ci) * 25 + dy * 5 + dx];
                    acc[cg][0] = fmaf(wv, p[dy][dx],     acc[cg][0]);
                    acc[cg][1] = fmaf(wv, p[dy][dx + 1], acc[cg][1]);
                }
            }
        }
    }

    int r = t / Wt;
    float m[COG];
#pragma unroll
    for (int cg = 0; cg < COG; ++cg) {
        float v0 = leaky(acc[cg][0]), v1 = leaky(acc[cg][1]);
        m[cg] = fmaxf(v0, v1);
        if (n >= 2) {
            float2 stv; stv.x = v0; stv.y = v1;
            *(float2*)(c2 + ((size_t)((n - 2) * CO + g * COG + cg)) * H * W + y * W + x0) = stv;
        }
    }
    if (r & 1) {
#pragma unroll
        for (int cg = 0; cg < COG; ++cg)
            pl[((r >> 1) * COG + cg) * Wt + col] = m[cg];
    }
    __syncthreads();
    if (!(r & 1)) {
#pragma unroll
        for (int cg = 0; cg < COG; ++cg) {
            float pv = fmaxf(m[cg], pl[((r >> 1) * COG + cg) * Wt + col]);
            pout[((size_t)(n * CO + g * COG + cg)) * Wt * Wt + (y >> 1) * Wt + col] = pv;
        }
    }
}

// ================= Attention: fused query gather + cosine similarity =================
template<int C, int RP, int SHIFT>
__global__ void __launch_bounds__(256) attn_k(
    const float* __restrict__ pool, const int* __restrict__ pts,
    float* __restrict__ out)
{
    constexpr int P = RP * RP;
    __shared__ float qs[32 * C];
    int t = threadIdx.x, b = blockIdx.y;
    if (t < 32) {
        int l = t;
        int py = pts[(b * 32 + l) * 2 + 0] >> SHIFT;
        int px = pts[(b * 32 + l) * 2 + 1] >> SHIFT;
        const float* qp = pool + (size_t)(b * C) * P + py * RP + px;
        float v[C]; float s = 0.f;
#pragma unroll
        for (int c = 0; c < C; ++c) { v[c] = qp[c * P]; s += v[c] * v[c]; }
        float invn = 1.f / fmaxf(sqrtf(s), 1e-8f);
#pragma unroll
        for (int c = 0; c < C; ++c) qs[l * C + c] = v[c] * invn;
    }
    __syncthreads();
    int p = blockIdx.x * 256 + t;
    const float* hp = pool + (size_t)((2 + b) * C) * P + p;
    float v[C]; float s = 0.f;
#pragma unroll
    for (int c = 0; c < C; ++c) { v[c] = hp[c * P]; s += v[c] * v[c]; }
    float invn2 = 1.f / fmaxf(sqrtf(s), 1e-8f);
#pragma unroll 4
    for (int l = 0; l < 32; ++l) {
        float d = 0.f;
#pragma unroll
        for (int c = 0; c < C; ++c) d = fmaf(v[c], qs[l * C + c], d);
        out[(size_t)(b * 32 + l) * P + p] = d * invn2;
    }
}

// ================= Decoder conv3x3 pad1, fused upsample+concat, 2x2 output tile ======
template<int R, int CP, int CF, int CO, int COG, bool TILEDPREV, bool DOLEAKY>
__global__ void __launch_bounds__(256) dec_k(
    const float* __restrict__ prev, const float* __restrict__ attn,
    const float* __restrict__ feat, const float* __restrict__ w,
    const float* __restrict__ bias, float* __restrict__ out)
{
    constexpr int CIN = CP + 1 + CF, Rh = R / 2;
    __shared__ float ws[COG * CIN * 9];
    int t = threadIdx.x, gid = blockIdx.x * 256 + t;
    int tx = gid % Rh;
    int ty = (gid / Rh) % Rh;
    int k = (gid / (Rh * Rh)) & 63;
    int g = gid / (Rh * Rh * 64);

    for (int i = t; i < COG * CIN * 9; i += 256) ws[i] = w[g * COG * CIN * 9 + i];
    __syncthreads();

    float acc[COG][2][2];
#pragma unroll
    for (int cg = 0; cg < COG; ++cg) {
        float b0 = bias[g * COG + cg];
        acc[cg][0][0] = b0; acc[cg][0][1] = b0; acc[cg][1][0] = b0; acc[cg][1][1] = b0;
    }

    bool hr[3], hc[3], fr[4], fc[4];
#pragma unroll
    for (int i = 0; i < 3; ++i) {
        int yy = ty - 1 + i; hr[i] = (yy >= 0) && (yy < Rh);
        int xx = tx - 1 + i; hc[i] = (xx >= 0) && (xx < Rh);
    }
#pragma unroll
    for (int i = 0; i < 4; ++i) {
        int yy = 2 * ty - 1 + i; fr[i] = (yy >= 0) && (yy < R);
        int xx = 2 * tx - 1 + i; fc[i] = (xx >= 0) && (xx < R);
    }

    constexpr int HM0[3] = {0, 1, 1};
    constexpr int HM1[3] = {1, 1, 2};

    int np = TILEDPREV ? (2 + (k & 1)) : k;
    int kf = k & 1;

    for (int ci = 0; ci < CP + 1; ++ci) {
        const float* bp = (ci < CP) ? (prev + ((size_t)(np * CP + ci)) * Rh * Rh)
                                    : (attn + (size_t)k * Rh * Rh);
        bp += (ty - 1) * Rh + (tx - 1);
        float P[3][3];
#pragma unroll
        for (int i = 0; i < 3; ++i)
#pragma unroll
            for (int j = 0; j < 3; ++j)
                P[i][j] = (hr[i] & hc[j]) ? bp[i * Rh + j] : 0.f;
#pragma unroll
        for (int cg = 0; cg < COG; ++cg) {
#pragma unroll
            for (int dy = 0; dy < 3; ++dy) {
#pragma unroll
                for (int dx = 0; dx < 3; ++dx) {
                    float wv = ws[(cg * CIN + ci) * 9 + dy * 3 + dx];
                    acc[cg][0][0] = fmaf(wv, P[HM0[dy]][HM0[dx]], acc[cg][0][0]);
                    acc[cg][0][1] = fmaf(wv, P[HM0[dy]][HM1[dx]], acc[cg][0][1]);
                    acc[cg][1][0] = fmaf(wv, P[HM1[dy]][HM0[dx]], acc[cg][1][0]);
                    acc[cg][1][1] = fmaf(wv, P[HM1[dy]][HM1[dx]], acc[cg][1][1]);
                }
            }
        }
    }

    for (int cf = 0; cf < CF; ++cf) {
        const float* bp = feat + ((size_t)(kf * CF + cf)) * R * R + (2 * ty - 1) * R + (2 * tx - 1);
        float F[4][4];
#pragma unroll
        for (int i = 0; i < 4; ++i)
#pragma unroll
            for (int j = 0; j < 4; ++j)
                F[i][j] = (fr[i] & fc[j]) ? bp[i * R + j] : 0.f;
#pragma unroll
        for (int cg = 0; cg < COG; ++cg) {
#pragma unroll
            for (int dy = 0; dy < 3; ++dy) {
#pragma unroll
                for (int dx = 0; dx < 3; ++dx) {
                    float wv = ws[(cg * CIN + CP + 1 + cf) * 9 + dy * 3 + dx];
                    acc[cg][0][0] = fmaf(wv, F[dy][dx],         acc[cg][0][0]);
                    acc[cg][0][1] = fmaf(wv, F[dy][dx + 1],     acc[cg][0][1]);
                    acc[cg][1][0] = fmaf(wv, F[dy + 1][dx],     acc[cg][1][0]);
                    acc[cg][1][1] = fmaf(wv, F[dy + 1][dx + 1], acc[cg][1][1]);
                }
            }
        }
    }

#pragma unroll
    for (int cg = 0; cg < COG; ++cg) {
        float v00 = acc[cg][0][0], v01 = acc[cg][0][1];
        float v10 = acc[cg][1][0], v11 = acc[cg][1][1];
        if (DOLEAKY) { v00 = leaky(v00); v01 = leaky(v01); v10 = leaky(v10); v11 = leaky(v11); }
        float* op = out + ((size_t)(k * CO + g * COG + cg)) * R * R + (2 * ty) * R + 2 * tx;
        float2 a; a.x = v00; a.y = v01; *(float2*)op = a;
        float2 b2; b2.x = v10; b2.y = v11; *(float2*)(op + R) = b2;
    }
}

// ================= Decoder conv3x3, fused upsample+concat, 4x4 output tile ===========
// Thread computes out[k][g*COG..][4qy..4qy+3][4qx..4qx+3].
// Half-res inputs: 4x4 patch at (2qy-1, 2qx-1); full-res feat: 6x6 at (4qy-1, 4qx-1).
// Subpixel tap (s = sub + d) -> half patch index (s+1)>>1; feat index s directly.
template<int R, int CP, int CF, int CO, int COG, bool TILEDPREV, bool DOLEAKY>
__global__ void __launch_bounds__(256) dec4_k(
    const float* __restrict__ prev, const float* __restrict__ attn,
    const float* __restrict__ feat, const float* __restrict__ w,
    const float* __restrict__ bias, float* __restrict__ out)
{
    constexpr int CIN = CP + 1 + CF, Rh = R / 2, Rq = R / 4;
    __shared__ float ws[COG * CIN * 9];
    int t = threadIdx.x, gid = blockIdx.x * 256 + t;
    int qx = gid % Rq;
    int qy = (gid / Rq) % Rq;
    int k = (gid / (Rq * Rq)) % 64;
    int g = gid / (Rq * Rq * 64);

    for (int i = t; i < COG * CIN * 9; i += 256) ws[i] = w[g * COG * CIN * 9 + i];
    __syncthreads();

    float acc[COG][4][4];
#pragma unroll
    for (int cg = 0; cg < COG; ++cg) {
        float b0 = bias[g * COG + cg];
#pragma unroll
        for (int sy = 0; sy < 4; ++sy)
#pragma unroll
            for (int sx = 0; sx < 4; ++sx) acc[cg][sy][sx] = b0;
    }

    bool hr[4], hc[4], fr[6], fc[6];
#pragma unroll
    for (int i = 0; i < 4; ++i) {
        int yy = 2 * qy - 1 + i; hr[i] = (yy >= 0) && (yy < Rh);
        int xx = 2 * qx - 1 + i; hc[i] = (xx >= 0) && (xx < Rh);
    }
#pragma unroll
    for (int i = 0; i < 6; ++i) {
        int yy = 4 * qy - 1 + i; fr[i] = (yy >= 0) && (yy < R);
        int xx = 4 * qx - 1 + i; fc[i] = (xx >= 0) && (xx < R);
    }

    int np = TILEDPREV ? (2 + (k & 1)) : k;
    int kf = k & 1;

    // half-res channels (prev, then attn)
    for (int ci = 0; ci < CP + 1; ++ci) {
        const float* bp = (ci < CP) ? (prev + ((size_t)(np * CP + ci)) * Rh * Rh)
                                    : (attn + (size_t)k * Rh * Rh);
        bp += (2 * qy - 1) * Rh + (2 * qx - 1);
        float P[4][4];
#pragma unroll
        for (int i = 0; i < 4; ++i)
#pragma unroll
            for (int j = 0; j < 4; ++j)
                P[i][j] = (hr[i] & hc[j]) ? bp[i * Rh + j] : 0.f;
#pragma unroll
        for (int cg = 0; cg < COG; ++cg) {
#pragma unroll
            for (int dy = 0; dy < 3; ++dy) {
#pragma unroll
                for (int dx = 0; dx < 3; ++dx) {
                    float wv = ws[(cg * CIN + ci) * 9 + dy * 3 + dx];
#pragma unroll
                    for (int sy = 0; sy < 4; ++sy) {
#pragma unroll
                        for (int sx = 0; sx < 4; ++sx) {
                            acc[cg][sy][sx] = fmaf(wv,
                                P[(sy + dy + 1) >> 1][(sx + dx + 1) >> 1],
                                acc[cg][sy][sx]);
                        }
                    }
                }
            }
        }
    }

    // full-res feat channels
    for (int cf = 0; cf < CF; ++cf) {
        const float* bp = feat + ((size_t)(kf * CF + cf)) * R * R + (4 * qy - 1) * R + (4 * qx - 1);
        float F[6][6];
#pragma unroll
        for (int i = 0; i < 6; ++i)
#pragma unroll
            for (int j = 0; j < 6; ++j)
                F[i][j] = (fr[i] & fc[j]) ? bp[i * R + j] : 0.f;
#pragma unroll
        for (int cg = 0; cg < COG; ++cg) {
#pragma unroll
            for (int dy = 0; dy < 3; ++dy) {
#pragma unroll
                for (int dx = 0; dx < 3; ++dx) {
                    float wv = ws[(cg * CIN + CP + 1 + cf) * 9 + dy * 3 + dx];
#pragma unroll
                    for (int sy = 0; sy < 4; ++sy) {
#pragma unroll
                        for (int sx = 0; sx < 4; ++sx) {
                            acc[cg][sy][sx] = fmaf(wv, F[sy + dy][sx + dx], acc[cg][sy][sx]);
                        }
                    }
                }
            }
        }
    }

#pragma unroll
    for (int cg = 0; cg < COG; ++cg) {
        float* op = out + ((size_t)(k * CO + g * COG + cg)) * R * R + (4 * qy) * R + 4 * qx;
#pragma unroll
        for (int sy = 0; sy < 4; ++sy) {
            float4 v;
            v.x = acc[cg][sy][0]; v.y = acc[cg][sy][1];
            v.z = acc[cg][sy][2]; v.w = acc[cg][sy][3];
            if (DOLEAKY) { v.x = leaky(v.x); v.y = leaky(v.y); v.z = leaky(v.z); v.w = leaky(v.w); }
            *(float4*)(op + sy * R) = v;
        }
    }
}

extern "C" void kernel_launch(void* const* d_in, const int* in_sizes, int n_in,
                              void* d_out, int out_size, void* d_ws, size_t ws_size,
                              hipStream_t stream)
{
    (void)in_sizes; (void)n_in; (void)out_size; (void)ws_size;
    const float* x1 = (const float*)d_in[0];
    const float* x2 = (const float*)d_in[1];
    const int* pts = (const int*)d_in[2];
    const float* ew[4] = {(const float*)d_in[3], (const float*)d_in[5],
                          (const float*)d_in[7], (const float*)d_in[9]};
    const float* eb[4] = {(const float*)d_in[4], (const float*)d_in[6],
                          (const float*)d_in[8], (const float*)d_in[10]};
    const float* dw[4] = {(const float*)d_in[11], (const float*)d_in[13],
                          (const float*)d_in[15], (const float*)d_in[17]};
    const float* db[4] = {(const float*)d_in[12], (const float*)d_in[14],
                          (const float*)d_in[16], (const float*)d_in[18]};

    float* wsp = (float*)d_ws;
    size_t off = 0;
    auto A = [&](size_t n) { float* p = wsp + off; off += n; return p; };

    // pooled activations, all 4 virtual images: [4][C][Rp][Rp]
    float* p0 = A((size_t)4 * 4 * 128 * 128);
    float* p1 = A((size_t)4 * 8 * 64 * 64);
    float* p2 = A((size_t)4 * 16 * 32 * 32);
    float* p3 = A((size_t)4 * 16 * 16 * 16);
    // pre-pool conv outputs, image-2 only: [2][C][R][R]
    float* c2_0 = A((size_t)2 * 4 * 256 * 256);
    float* c2_1 = A((size_t)2 * 8 * 128 * 128);
    float* c2_2 = A((size_t)2 * 16 * 64 * 64);
    float* c2_3 = A((size_t)2 * 16 * 32 * 32);
    // attention maps [64][Rp][Rp]
    float* at0 = A((size_t)64 * 128 * 128);
    float* at1 = A((size_t)64 * 64 * 64);
    float* at2 = A((size_t)64 * 32 * 32);
    float* at3 = A((size_t)64 * 16 * 16);
    // decoder intermediates
    float* dec0 = A((size_t)64 * 16 * 32 * 32);
    float* dec1 = A((size_t)64 * 8 * 64 * 64);
    float* dec2 = A((size_t)64 * 4 * 128 * 128);
    float* outp = (float*)d_out;

    // ---- Encoder (4 virtual images per launch, conv+leaky+pool fused) ----
    enc_k<256, 3, 4, 2><<<1024, 256, 0, stream>>>(x1, x2, ew[0], eb[0], c2_0, p0);
    enc_k<128, 4, 8, 2><<<512, 256, 0, stream>>>(p0, p0 + (size_t)2 * 4 * 128 * 128,
                                                 ew[1], eb[1], c2_1, p1);
    enc_k<64, 8, 16, 2><<<256, 256, 0, stream>>>(p1, p1 + (size_t)2 * 8 * 64 * 64,
                                                 ew[2], eb[2], c2_2, p2);
    enc_k<32, 16, 16, 1><<<128, 256, 0, stream>>>(p2, p2 + (size_t)2 * 16 * 32 * 32,
                                                  ew[3], eb[3], c2_3, p3);

    // ---- Attention (query gather fused) ----
    { dim3 g(64, 2); attn_k<4, 128, 1><<<g, 256, 0, stream>>>(p0, pts, at0); }
    { dim3 g(16, 2); attn_k<8, 64, 2><<<g, 256, 0, stream>>>(p1, pts, at1); }
    { dim3 g(4, 2);  attn_k<16, 32, 3><<<g, 256, 0, stream>>>(p2, pts, at2); }
    { dim3 g(1, 2);  attn_k<16, 16, 4><<<g, 256, 0, stream>>>(p3, pts, at3); }

    // ---- Decoder (fused upsample+concat) ----
    // dec0: 2x2 tiles, COG=8 (2 groups): threads = 64*16*16*2 = 32768
    dec_k<32, 16, 16, 16, 8, true, true><<<128, 256, 0, stream>>>(p3, at3, c2_3, dw[0], db[0], dec0);
    // dec1: 2x2 tiles, COG=8 (1 group): threads = 64*32*32 = 65536
    dec_k<64, 16, 16, 8, 8, false, true><<<256, 256, 0, stream>>>(dec0, at2, c2_2, dw[1], db[1], dec1);
    // dec2: 4x4 tiles, COG=4 (1 group): threads = 64*32*32 = 65536
    dec4_k<128, 8, 8, 4, 4, false, true><<<256, 256, 0, stream>>>(dec1, at1, c2_1, dw[2], db[2], dec2);
    // dec3: 4x4 tiles, COG=1: threads = 64*64*64 = 262144
    dec4_k<256, 4, 4, 1, 1, false, false><<<1024, 256, 0, stream>>>(dec2, at0, c2_0, dw[3], db[3], outp);
}